// Round 20
// baseline (146.349 us; speedup 1.0000x reference)
//
#include <hip/hip_runtime.h>

// SelfAttention (SAGAN-style) on MI355X.
// B=2, C=64, C8=8, H=W=96, N=9216.  out = gamma * Attn(g,f,h) + x
//   K = f = (Wq/sq) x + bq   (pre-scaled by log2e; softmax in exp2 domain)
//   Q = g = (Wk/sk) x + bk
//   V = h = (Wv/sv) x + bv
// softmax over keys i; head_dim 8 (zero-padded), dv=64.
//
// R32: l-sum moved from VALU to the idle MFMA pipe. R31 confirmed the
// R28 baseline (142.5us; k_attn 52.6 @ VALU 47% / MFMA 20% -- VALU issue
// is the busiest resource, matrix pipe idles). The softmax denominator
// is a column-sum of P: acc_l = mfma(ones, P, acc_l) computes it with
// every output row identical (= sum_k P[k][query], col = lane&31), so
// readout is layout-proof: ls = acc_l[0] in every lane, no shuffles.
// 4 extra MFMAs/round (~32cy, 20%-busy pipe) replace 32 v_add_f32
// (~64cy, 47%-busy pipe) + epilogue shfl_xor. Denominator now sums the
// f16-rounded P -- the same values the numerator PV-MFMA consumes
// (more self-consistent; |delta| << 0.03 current absmax). Pure
// arithmetic restructure: no scheduling/slot/fence/unroll change (the
// only class of change that has passed every time this session).
// Loop protocol unchanged: rolled (depth-1 REQUIRED: slot dbuf+vmcnt(5)
// WAR), plain partial writes, 3 dispatches (boundary floor).
// Numerics: M = |Q|*max|K'| - 12, f16 P, f32 lsum (now via MFMA).

#define N_PIX 9216
#define N_B   2
#define N_C   64

typedef _Float16 half8  __attribute__((ext_vector_type(8)));
typedef float    float4v __attribute__((ext_vector_type(4)));
typedef float    float16v __attribute__((ext_vector_type(16)));
typedef int      int4v  __attribute__((ext_vector_type(4)));

#define LOG2E 1.44269504088896340736f
#define EXP_SHIFT 12.0f
#define LGKM0() asm volatile("s_waitcnt lgkmcnt(0)" ::: "memory")

// ---------------------------------------------------------------- k_fgh
// (byte-identical to R28/R31)
// 288 blocks x 256 thr: block = (b, 64-pixel span n0).
// Phase A (waves in parallel): sigmas (w0: Wq, w1: Wk, w2: Wv-MFMA) + x->Xh (w3).
// Phase B: Wsh = W/sigma in f16, MFMA f/g/h, staged coalesced stores.
// Writes Kmax[b*144+t144] (deterministic, no atomics).
__global__ __launch_bounds__(256) void k_fgh(const float* __restrict__ x,
                                             const float* __restrict__ Wq, const float* __restrict__ bq,
                                             const float* __restrict__ Wk, const float* __restrict__ bk,
                                             const float* __restrict__ Wv, const float* __restrict__ bv,
                                             _Float16* __restrict__ K16,
                                             _Float16* __restrict__ Q16,
                                             _Float16* __restrict__ VT16,
                                             float* __restrict__ Kmax) {
  __shared__ __align__(16) char SMEM[46624];
  _Float16* Xh  = (_Float16*)SMEM;                    // [64][72] = 9216 B (persist)
  float*    Wl  = (float*)(SMEM + 9216);              // 4096 f32 = 16384 B
  _Float16* Wh  = (_Float16*)(SMEM + 25600);          // [64][80] = 10240 B
  _Float16* Gh  = (_Float16*)(SMEM + 35840);          // [64][80] = 10240 B
  float*    G8q = (float*)(SMEM + 46080);             // 64 f32 (phase A)
  float*    G8k = (float*)(SMEM + 46336);             // 64 f32
  float*    sigs = (float*)(SMEM + 46592);            // 4 f32
  _Float16* Wsh = (_Float16*)(SMEM + 9216);           // [80][64] = 10240 B
  float*    bsh = (float*)(SMEM + 19456);             // 80 f32
  _Float16* Rt  = (_Float16*)(SMEM + 19776);          // [80][72] = 11520 B
  float*    kmx = (float*)(SMEM + 46080);             // 4 f32 (phase B, reuses G8q)

  const int t = threadIdx.x;
  const int wave = t >> 6, lane = t & 63;
  const int tile = blockIdx.x;
  const int b = tile / 144;
  const int t144 = tile % 144;
  const int n0 = t144 * 64;
  const float* xb = x + (size_t)b * N_C * N_PIX;

  // ================= Phase A =================
  if (wave == 3) {
#pragma unroll
    for (int i = 0; i < 16; ++i) {
      const int idx = lane + 64 * i;       // 0..1023
      const int c = idx >> 4, f4 = idx & 15;
      const float4v v = *(const float4v*)(xb + (size_t)c * N_PIX + n0 + 4 * f4);
#pragma unroll
      for (int e = 0; e < 4; ++e) Xh[(4 * f4 + e) * 72 + c] = (_Float16)v[e];
    }
  } else if (wave < 2) {
    const float* W = (wave == 0) ? Wq : Wk;
    float* G8 = (wave == 0) ? G8q : G8k;
    const int i = lane >> 3, j = lane & 7;
    float g = 0.f;
    for (int c = 0; c < 64; ++c) g += W[i * 64 + c] * W[j * 64 + c];
    G8[lane] = g;
    LGKM0();
    const int L = lane & 7;
    float G0[8], Gr[8];
    for (int k = 0; k < 8; ++k) { G0[k] = G8[L * 8 + k]; Gr[k] = G0[k]; }
    for (int it = 0; it < 8; ++it) {
      float g2[8] = {0, 0, 0, 0, 0, 0, 0, 0};
      for (int k = 0; k < 8; ++k) {
        float gik = Gr[k];
        for (int jj = 0; jj < 8; ++jj) g2[jj] += gik * __shfl(Gr[jj], k, 64);
      }
      float mx = 0.f;
      for (int jj = 0; jj < 8; ++jj) mx = fmaxf(mx, fabsf(g2[jj]));
      for (int d = 1; d < 8; d <<= 1) mx = fmaxf(mx, __shfl_xor(mx, d, 64));
      float r = 1.f / mx;
      for (int jj = 0; jj < 8; ++jj) Gr[jj] = g2[jj] * r;
    }
    float u = 0.f;
    for (int jj = 0; jj < 8; ++jj) u += Gr[jj];
    float y = 0.f;
    for (int k = 0; k < 8; ++k) y += G0[k] * __shfl(u, k, 64);
    float nu = u * y, de = u * u;
    for (int d = 1; d < 8; d <<= 1) { nu += __shfl_xor(nu, d, 64); de += __shfl_xor(de, d, 64); }
    if (lane == 0) sigs[wave] = sqrtf(nu / de);
  } else {
#pragma unroll
    for (int i = 0; i < 16; ++i) {
      const int idx = lane + 64 * i;
      *(float4v*)&Wl[4 * idx] = *(const float4v*)&Wv[4 * idx];
    }
    LGKM0();
    for (int idx = lane; idx < 4096; idx += 64)
      Wh[(idx >> 6) * 80 + (idx & 63)] = (_Float16)Wl[idx];
    LGKM0();
    const int lane15 = lane & 15, quad = lane >> 4;
    half8 fr[4][2];
    for (int rb = 0; rb < 4; ++rb)
      for (int kc = 0; kc < 2; ++kc)
        fr[rb][kc] = *(const half8*)&Wh[(lane15 + 16 * rb) * 80 + 32 * kc + 8 * quad];
    float4v D[4][4];
    for (int mb = 0; mb < 4; ++mb) for (int nb = 0; nb < 4; ++nb) D[mb][nb] = (float4v){0.f, 0.f, 0.f, 0.f};
    for (int kc = 0; kc < 2; ++kc)
      for (int mb = 0; mb < 4; ++mb)
        for (int nb = 0; nb < 4; ++nb)
          D[mb][nb] = __builtin_amdgcn_mfma_f32_16x16x32_f16(fr[mb][kc], fr[nb][kc], D[mb][nb], 0, 0, 0);
    for (int it = 0; it < 8; ++it) {
      float mx = 0.f;
      for (int mb = 0; mb < 4; ++mb) for (int nb = 0; nb < 4; ++nb) for (int r = 0; r < 4; ++r)
        mx = fmaxf(mx, fabsf(D[mb][nb][r]));
      for (int d = 1; d < 64; d <<= 1) mx = fmaxf(mx, __shfl_xor(mx, d, 64));
      const float rs = 1.f / mx;
      LGKM0();
      for (int mb = 0; mb < 4; ++mb) for (int nb = 0; nb < 4; ++nb) for (int r = 0; r < 4; ++r)
        Gh[(4 * quad + r + 16 * mb) * 80 + lane15 + 16 * nb] = (_Float16)(D[mb][nb][r] * rs);
      LGKM0();
      if (it == 7) break;
      for (int rb = 0; rb < 4; ++rb)
        for (int kc = 0; kc < 2; ++kc)
          fr[rb][kc] = *(const half8*)&Gh[(lane15 + 16 * rb) * 80 + 32 * kc + 8 * quad];
      for (int mb = 0; mb < 4; ++mb) for (int nb = 0; nb < 4; ++nb) D[mb][nb] = (float4v){0.f, 0.f, 0.f, 0.f};
      for (int kc = 0; kc < 2; ++kc)
        for (int mb = 0; mb < 4; ++mb)
          for (int nb = 0; nb < 4; ++nb)
            D[mb][nb] = __builtin_amdgcn_mfma_f32_16x16x32_f16(fr[mb][kc], fr[nb][kc], D[mb][nb], 0, 0, 0);
    }
    float u = 0.f;
    for (int c = 0; c < 64; ++c) u += (float)Gh[lane * 80 + c];
    float z = 0.f;
    for (int i2 = 0; i2 < 64; ++i2) z += Wl[i2 * 64 + lane] * __shfl(u, i2, 64);
    float nu = z * z, de = u * u;
    for (int d = 1; d < 64; d <<= 1) { nu += __shfl_xor(nu, d, 64); de += __shfl_xor(de, d, 64); }
    if (lane == 0) sigs[2] = sqrtf(nu / de);
  }
  __syncthreads();

  // ================= Phase B =================
  const float iq = LOG2E / sigs[0], ik = 1.0f / sigs[1], iv = 1.0f / sigs[2];
  __syncthreads();                         // sigs read before overlay reuse
  for (int idx = t; idx < 80 * 64; idx += 256) {
    const int m = idx >> 6, c = idx & 63;
    float v;
    if (m < 8)       v = Wq[m * 64 + c] * iq;
    else if (m < 16) v = Wk[(m - 8) * 64 + c] * ik;
    else             v = Wv[(m - 16) * 64 + c] * iv;
    Wsh[idx] = (_Float16)v;
  }
  if (t < 80) {
    float v;
    if (t < 8)       v = bq[t] * LOG2E;
    else if (t < 16) v = bk[t - 8];
    else             v = bv[t - 16];
    bsh[t] = v;
  }
  __syncthreads();
  const int lane15 = lane & 15, quad = lane >> 4;
  const int nl = 16 * wave + lane15;
  half8 wf[5][2];
  for (int mb = 0; mb < 5; ++mb)
    for (int kc = 0; kc < 2; ++kc)
      wf[mb][kc] = *(const half8*)&Wsh[(lane15 + 16 * mb) * 64 + 32 * kc + 8 * quad];
  float4v acc[5];
  for (int mb = 0; mb < 5; ++mb) acc[mb] = *(const float4v*)&bsh[16 * mb + 4 * quad];
  for (int kc = 0; kc < 2; ++kc) {
    const half8 bf = *(const half8*)&Xh[nl * 72 + 32 * kc + 8 * quad];
    for (int mb = 0; mb < 5; ++mb)
      acc[mb] = __builtin_amdgcn_mfma_f32_16x16x32_f16(wf[mb][kc], bf, acc[mb], 0, 0, 0);
  }
#pragma unroll
  for (int r = 0; r < 4; ++r) Rt[(4 * quad + r) * 72 + nl] = (_Float16)acc[0][r];
  for (int mb = 1; mb < 5; ++mb)
#pragma unroll
    for (int r = 0; r < 4; ++r) {
      const int c = 4 * quad + r + 16 * (mb - 1);
      Rt[(16 + c) * 72 + nl] = (_Float16)acc[mb][r];
    }
  // block max of ||K_pix||^2 -> Kmax (deterministic).
  float sq = 0.f;
  if (quad < 2)
    for (int r = 0; r < 4; ++r) sq += acc[0][r] * acc[0][r];
  sq += __shfl_xor(sq, 16, 64);
  for (int d = 1; d < 64; d <<= 1) sq = fmaxf(sq, __shfl_xor(sq, d, 64));
  if (lane == 0) kmx[wave] = sq;
  __syncthreads();
  if (t == 0) Kmax[b * 144 + t144] = fmaxf(fmaxf(kmx[0], kmx[1]), fmaxf(kmx[2], kmx[3]));
  if (t < 64) {                            // K16[n][0..8): dwordx4/thread
    const int n = t;
    int4v dw;
#pragma unroll
    for (int mw = 0; mw < 4; ++mw) {
      const unsigned lo = (unsigned)__builtin_bit_cast(unsigned short, Rt[(2 * mw) * 72 + n]);
      const unsigned hi = (unsigned)__builtin_bit_cast(unsigned short, Rt[(2 * mw + 1) * 72 + n]);
      dw[mw] = (int)(lo | (hi << 16));
    }
    *(int4v*)(K16 + ((size_t)b * N_PIX + n0 + n) * 8) = dw;
  } else if (t < 128) {                    // Q16[n][0..8)
    const int n = t - 64;
    int4v dw;
#pragma unroll
    for (int mw = 0; mw < 4; ++mw) {
      const unsigned lo = (unsigned)__builtin_bit_cast(unsigned short, Rt[(8 + 2 * mw) * 72 + n]);
      const unsigned hi = (unsigned)__builtin_bit_cast(unsigned short, Rt[(9 + 2 * mw) * 72 + n]);
      dw[mw] = (int)(lo | (hi << 16));
    }
    *(int4v*)(Q16 + ((size_t)b * N_PIX + n0 + n) * 8) = dw;
  }
  {                                        // VT16[c][n0..+64): 32B/thread
    const int c = t >> 2, part = t & 3;
    const _Float16* src = &Rt[(16 + c) * 72 + 16 * part];
    const int4v a = *(const int4v*)src;
    const int4v b2 = *(const int4v*)(src + 8);
    _Float16* dst = VT16 + ((size_t)b * N_C + c) * N_PIX + n0 + 16 * part;
    *(int4v*)dst = a;
    *(int4v*)(dst + 8) = b2;
  }
}

// ---------------------------------------------------------------- k_attn
// 864 blocks x 256 threads (4 waves): tile = b*432 + qt*3 + h; block covers
// queries [qt*64, +64) (two 32-q tiles) and keys [3072h, +3072), 24 rounds
// of 128 keys (wave w owns 32). K in regs (dbuf); V dbuf in LDS per wave
// (swizzled). Rolled loop (depth-1 REQUIRED: slot dbuf + vmcnt(5) WAR).
// l-sum via ones-MFMA into acc_l (col=query, all rows identical ->
// readout acc_l[0], no shuffles). Plain partial writes, no fences.

__device__ __forceinline__ void gload16(const _Float16* g, _Float16* l) {
  __builtin_amdgcn_global_load_lds(
      (const __attribute__((address_space(1))) void*)g,
      (__attribute__((address_space(3))) void*)l, 16, 0, 0);
}
#define VMWAIT5() asm volatile("s_waitcnt vmcnt(5)" ::: "memory")

// v_permlane32_swap_b32: a' = [a.lo, b.lo], b' = [a.hi, b.hi]
__device__ __forceinline__ void plswap(int& a, int& b) {
  asm("v_permlane32_swap_b32 %0, %1" : "+v"(a), "+v"(b));
}

__global__ __launch_bounds__(256, 2) void k_attn(const _Float16* __restrict__ K16,
                                                 const _Float16* __restrict__ Q16,
                                                 const _Float16* __restrict__ VT16,
                                                 const float* __restrict__ Kmax,
                                                 float* __restrict__ Opart,
                                                 float* __restrict__ Lpart) {
  __shared__ __align__(16) _Float16 SM[4][4096];   // 32768 B -> 4 blocks/CU
  const int wave = threadIdx.x >> 6;      // 0..3
  const int lane = threadIdx.x & 63;
  const int q31 = lane & 31, hi = lane >> 5;
  const int tile = blockIdx.x;            // 0..863
  const int b = tile / 432;
  const int rm = tile % 432;
  const int qt = rm / 3;                  // 0..143 -> queries [qt*64, +64)
  const int h = rm % 3;                   // key split
  const int jb = qt * 64;
  const int kh = h * (N_PIX / 3);         // 3072-key range base
  const _Float16* Kb = K16 + (size_t)b * N_PIX * 8;
  const _Float16* Vb = VT16 + (size_t)b * N_C * N_PIX;
  _Float16* Rg = SM[wave];
  const int cl = lane >> 2, kk = lane & 3;
  const int gsw = (kk ^ ((cl >> 1) & 3)) * 8;
  const int vx = (q31 >> 1) & 3;
  const int voff00 = q31 * 32 + ((hi ^ vx) << 3);
  const int voff01 = q31 * 32 + (((2 + hi) ^ vx) << 3);
  const int voff10 = 1024 + voff00;
  const int voff11 = 1024 + voff01;

  half8 qfA = {}, qfB = {};
  if (hi == 0) {
    qfA = *(const half8*)(Q16 + ((size_t)b * N_PIX + jb + q31) * 8);
    qfB = *(const half8*)(Q16 + ((size_t)b * N_PIX + jb + 32 + q31) * 8);
  }
  // deterministic max||K||^2 over the batch: reduce 144 per-tile maxima.
  float km;
  {
    const float* Km = Kmax + b * 144;
    const float a0 = Km[lane];
    const float a1 = Km[64 + lane];
    const float a2 = (lane < 16) ? Km[128 + lane] : 0.f;
    km = fmaxf(fmaxf(a0, a1), a2);
    for (int d = 1; d < 64; d <<= 1) km = fmaxf(km, __shfl_xor(km, d, 64));
  }
  const float maxK = sqrtf(km);
  float nqA = 0.f, nqB = 0.f;
#pragma unroll
  for (int j = 0; j < 8; ++j) {
    nqA += (float)qfA[j] * (float)qfA[j];
    nqB += (float)qfB[j] * (float)qfB[j];
  }
  nqA += __shfl_xor(nqA, 32, 64);
  nqB += __shfl_xor(nqB, 32, 64);
  const float MA = sqrtf(nqA) * maxK - EXP_SHIFT;
  const float MB = sqrtf(nqB) * maxK - EXP_SHIFT;
  float16v sinitA, sinitB;
#pragma unroll
  for (int r2 = 0; r2 < 16; ++r2) { sinitA[r2] = -MA; sinitB[r2] = -MB; }

  float16v accLo0 = {}, accHi0 = {}, accLo1 = {}, accHi1 = {};
  float16v acc_lA = {}, acc_lB = {};      // l-sum accumulators (ones-MFMA)
  const half8 ones = {(_Float16)1, (_Float16)1, (_Float16)1, (_Float16)1,
                      (_Float16)1, (_Float16)1, (_Float16)1, (_Float16)1};

  // softmax: S (f32x16, C-layout, already -M biased) -> P0/P1 (B-layout f16).
  // l-sum is NOT accumulated here (moved to ones-MFMA on P in the loop).
  auto softmax = [&](const float16v& s, half8& P0, half8& P1) {
    int pk[8];
#pragma unroll
    for (int u = 0; u < 8; ++u) {
      const float p0 = __builtin_amdgcn_exp2f(s[2 * u]);
      const float p1 = __builtin_amdgcn_exp2f(s[2 * u + 1]);
      pk[u] = __builtin_bit_cast(int, __builtin_amdgcn_cvt_pkrtz(p0, p1));
    }
    int p0w = pk[0], p2w = pk[2];  plswap(p0w, p2w);
    int p1w = pk[1], p3w = pk[3];  plswap(p1w, p3w);
    int p4w = pk[4], p6w = pk[6];  plswap(p4w, p6w);
    int p5w = pk[5], p7w = pk[7];  plswap(p5w, p7w);
    int4v B0i, B1i;
    B0i[0] = p0w; B0i[1] = p1w; B0i[2] = p2w; B0i[3] = p3w;
    B1i[0] = p4w; B1i[1] = p5w; B1i[2] = p6w; B1i[3] = p7w;
    P0 = __builtin_bit_cast(half8, B0i);
    P1 = __builtin_bit_cast(half8, B1i);
  };

#define STAGEV(SLOT, I0)                                                         \
  {                                                                              \
    const int _i = (I0);                                                         \
    gload16(Vb + (size_t)cl * N_PIX + _i + gsw,        Rg + (SLOT) * 2048);      \
    gload16(Vb + (size_t)(16 + cl) * N_PIX + _i + gsw, Rg + (SLOT) * 2048 + 512);\
    gload16(Vb + (size_t)(32 + cl) * N_PIX + _i + gsw, Rg + (SLOT) * 2048 + 1024);\
    gload16(Vb + (size_t)(48 + cl) * N_PIX + _i + gsw, Rg + (SLOT) * 2048 + 1536);\
  }

  // K base for this wave's key stream; +1024 halves (128 keys) per round.
  const _Float16* kpt = Kb + (size_t)(kh + 32 * wave + q31) * 8;
  int4v kcur = *(const int4v*)kpt;
  STAGEV(0, kh + 32 * wave)

#pragma unroll 1
  for (int r = 0; r < 24; ++r) {
    const int slot = r & 1, nslot = slot ^ 1;
    // prefetch round r+1 (r=23: clamp -> re-load round 23, never consumed)
    const int rn = (r < 23) ? (r + 1) : 23;
    int4v knext = *(const int4v*)(kpt + (size_t)rn * 1024);
    STAGEV(nslot, kh + 128 * rn + 32 * wave)
    VMWAIT5();
    int4v kcz;
    kcz[0] = hi ? 0 : kcur[0];
    kcz[1] = hi ? 0 : kcur[1];
    kcz[2] = hi ? 0 : kcur[2];
    kcz[3] = hi ? 0 : kcur[3];
    const half8 kf = __builtin_bit_cast(half8, kcz);
    float16v sA = __builtin_amdgcn_mfma_f32_32x32x16_f16(kf, qfA, sinitA, 0, 0, 0);
    half8 P0a, P1a;
    softmax(sA, P0a, P1a);
    float16v sB = __builtin_amdgcn_mfma_f32_32x32x16_f16(kf, qfB, sinitB, 0, 0, 0);
    half8 P0b, P1b;
    softmax(sB, P0b, P1b);
    const _Float16* Vs = Rg + slot * 2048;
    const half8 v00 = *(const half8*)&Vs[voff00];
    const half8 v01 = *(const half8*)&Vs[voff01];
    const half8 v10 = *(const half8*)&Vs[voff10];
    const half8 v11 = *(const half8*)&Vs[voff11];
    accLo0 = __builtin_amdgcn_mfma_f32_32x32x16_f16(v00, P0a, accLo0, 0, 0, 0);
    accLo0 = __builtin_amdgcn_mfma_f32_32x32x16_f16(v01, P1a, accLo0, 0, 0, 0);
    accHi0 = __builtin_amdgcn_mfma_f32_32x32x16_f16(v10, P0a, accHi0, 0, 0, 0);
    accHi0 = __builtin_amdgcn_mfma_f32_32x32x16_f16(v11, P1a, accHi0, 0, 0, 0);
    accLo1 = __builtin_amdgcn_mfma_f32_32x32x16_f16(v00, P0b, accLo1, 0, 0, 0);
    accLo1 = __builtin_amdgcn_mfma_f32_32x32x16_f16(v01, P1b, accLo1, 0, 0, 0);
    accHi1 = __builtin_amdgcn_mfma_f32_32x32x16_f16(v10, P0b, accHi1, 0, 0, 0);
    accHi1 = __builtin_amdgcn_mfma_f32_32x32x16_f16(v11, P1b, accHi1, 0, 0, 0);
    // l-sum on the MFMA pipe: every output row = sum_k P[k][query].
    acc_lA = __builtin_amdgcn_mfma_f32_32x32x16_f16(ones, P0a, acc_lA, 0, 0, 0);
    acc_lA = __builtin_amdgcn_mfma_f32_32x32x16_f16(ones, P1a, acc_lA, 0, 0, 0);
    acc_lB = __builtin_amdgcn_mfma_f32_32x32x16_f16(ones, P0b, acc_lB, 0, 0, 0);
    acc_lB = __builtin_amdgcn_mfma_f32_32x32x16_f16(ones, P1b, acc_lB, 0, 0, 0);
    kcur = knext;
  }
#undef STAGEV
  asm volatile("s_waitcnt vmcnt(0)" ::: "memory");

  // ---- cross-wave merge (4 passes over 4 waves), partials undivided.
  float* Ow  = (float*)Rg;               // 64 x 17 f32 (stride 17: bank-free)
  float* LwA = (float*)Rg + 1100;        // 32 f32
  float* LwB = (float*)Rg + 1140;        // 32 f32
  const float lsA = acc_lA[0];           // identical in all lanes' reg 0
  const float lsB = acc_lB[0];
  if (hi == 0) { LwA[q31] = lsA; LwB[q31] = lsB; }
  float* Op0 = Opart + (size_t)(tile * 2) * 2048;     // sub-tile A
  float* Op1 = Op0 + 2048;                            // sub-tile B
#pragma unroll
  for (int r2 = 0; r2 < 16; ++r2) Ow[lane * 17 + r2] = accLo0[r2];
  __syncthreads();
  float ltotA = 0.f, ltotB = 0.f;
#pragma unroll
  for (int w = 0; w < 4; ++w) {
    ltotA += ((const float*)SM[w])[1100 + q31];
    ltotB += ((const float*)SM[w])[1140 + q31];
  }
  if (wave == 0 && hi == 0) {
    Lpart[(tile * 2) * 32 + q31] = ltotA;
    Lpart[(tile * 2 + 1) * 32 + q31] = ltotB;
  }
#pragma unroll
  for (int r2 = 0; r2 < 16; ++r2) {
    float osum = 0.f;
#pragma unroll
    for (int w = 0; w < 4; ++w) osum += ((const float*)SM[w])[lane * 17 + r2];
    const int c = (r2 & 3) + 8 * (r2 >> 2) + 4 * hi;
    Op0[c * 32 + q31] = osum;
  }
  __syncthreads();
#pragma unroll
  for (int r2 = 0; r2 < 16; ++r2) Ow[lane * 17 + r2] = accHi0[r2];
  __syncthreads();
#pragma unroll
  for (int r2 = 0; r2 < 16; ++r2) {
    float osum = 0.f;
#pragma unroll
    for (int w = 0; w < 4; ++w) osum += ((const float*)SM[w])[lane * 17 + r2];
    const int c = 32 + (r2 & 3) + 8 * (r2 >> 2) + 4 * hi;
    Op0[c * 32 + q31] = osum;
  }
  __syncthreads();
#pragma unroll
  for (int r2 = 0; r2 < 16; ++r2) Ow[lane * 17 + r2] = accLo1[r2];
  __syncthreads();
#pragma unroll
  for (int r2 = 0; r2 < 16; ++r2) {
    float osum = 0.f;
#pragma unroll
    for (int w = 0; w < 4; ++w) osum += ((const float*)SM[w])[lane * 17 + r2];
    const int c = (r2 & 3) + 8 * (r2 >> 2) + 4 * hi;
    Op1[c * 32 + q31] = osum;
  }
  __syncthreads();
#pragma unroll
  for (int r2 = 0; r2 < 16; ++r2) Ow[lane * 17 + r2] = accHi1[r2];
  __syncthreads();
#pragma unroll
  for (int r2 = 0; r2 < 16; ++r2) {
    float osum = 0.f;
#pragma unroll
    for (int w = 0; w < 4; ++w) osum += ((const float*)SM[w])[lane * 17 + r2];
    const int c = 32 + (r2 & 3) + 8 * (r2 >> 2) + 4 * hi;
    Op1[c * 32 + q31] = osum;
  }
}

// ---------------------------------------------------------------- k_merge
// 576 blocks (b, jt32): out = gm*(sum of 3 key-split partials)/(l sum) + x.
__global__ __launch_bounds__(256) void k_merge(const float* __restrict__ Opart,
                                               const float* __restrict__ Lpart,
                                               const float* __restrict__ x,
                                               const float* __restrict__ gamma,
                                               float* __restrict__ out) {
  __shared__ float Ls[32];
  const int t2 = blockIdx.x;              // 0..575
  const int b = t2 / 288, jt = t2 % 288;  // jt: 32-query tile index
  const int jb = jt * 32;
  const int qt = jt >> 1, sub = jt & 1;
  const int g0 = b * 432 + qt * 3;        // 3 key-split partials
  const float gm = gamma[0];
  const int t = threadIdx.x;
  if (t < 32)
    Ls[t] = Lpart[((g0 + 0) * 2 + sub) * 32 + t] +
            Lpart[((g0 + 1) * 2 + sub) * 32 + t] +
            Lpart[((g0 + 2) * 2 + sub) * 32 + t];
  __syncthreads();
  const float* O0 = Opart + (size_t)((g0 + 0) * 2 + sub) * 2048;
  const float* O1 = Opart + (size_t)((g0 + 1) * 2 + sub) * 2048;
  const float* O2 = Opart + (size_t)((g0 + 2) * 2 + sub) * 2048;
  const float* xb = x + (size_t)b * N_C * N_PIX;
  float* ob = out + (size_t)b * N_C * N_PIX;
#pragma unroll
  for (int k = 0; k < 8; ++k) {
    const int idx = t + 256 * k;
    const int c = idx >> 5, q = idx & 31;
    const size_t gi = (size_t)c * N_PIX + jb + q;
    ob[gi] = gm * (O0[idx] + O1[idx] + O2[idx]) / Ls[q] + xb[gi];
  }
}

// ---------------------------------------------------------------- launch
extern "C" void kernel_launch(void* const* d_in, const int* in_sizes, int n_in,
                              void* d_out, int out_size, void* d_ws, size_t ws_size,
                              hipStream_t stream) {
  const float* x     = (const float*)d_in[0];
  const float* Wq    = (const float*)d_in[1];
  const float* bq    = (const float*)d_in[2];
  const float* Wk    = (const float*)d_in[3];
  const float* bk    = (const float*)d_in[4];
  const float* Wv    = (const float*)d_in[5];
  const float* bv    = (const float*)d_in[6];
  const float* gamma = (const float*)d_in[7];
  float* out = (float*)d_out;

  char* ws = (char*)d_ws;
  float*    Kmax  = (float*)ws;                       // 288 f32 = 1152 B
  _Float16* K16   = (_Float16*)(ws + 10752);          // 294912 B
  _Float16* Q16   = (_Float16*)(ws + 10752 + 294912); // 294912 B
  _Float16* VT16  = (_Float16*)(ws + 10752 + 2 * 294912); // 2359296 B
  float*    Opart = (float*)(ws + 2960384);           // 864*2*2048*4 = 14155776 B
  float*    Lpart = (float*)(ws + 2960384 + 14155776); // 864*2*32*4 = 221184 B

  hipLaunchKernelGGL(k_fgh, dim3(288), dim3(256), 0, stream,
                     x, Wq, bq, Wk, bk, Wv, bv, K16, Q16, VT16, Kmax);
  hipLaunchKernelGGL(k_attn, dim3(864), dim3(256), 0, stream,
                     K16, Q16, VT16, Kmax, Opart, Lpart);
  hipLaunchKernelGGL(k_merge, dim3(576), dim3(256), 0, stream, Opart, Lpart, x, gamma, out);
}

// Round 21
// 140.803 us; speedup vs baseline: 1.0394x; 1.0394x over previous
//
#include <hip/hip_runtime.h>

// SelfAttention (SAGAN-style) on MI355X.
// B=2, C=64, C8=8, H=W=96, N=9216.  out = gamma * Attn(g,f,h) + x
//   K = f = (Wq/sq) x + bq   (pre-scaled by log2e; softmax in exp2 domain)
//   Q = g = (Wk/sk) x + bk
//   V = h = (Wv/sv) x + bv
// softmax over keys i; head_dim 8 (zero-padded), dv=64.
//
// R33 (FINAL): revert to R28/R31, the measured optimum (141.7/142.5us).
// R32 (l-sum via ones-MFMA) matched its counter prediction (VALU 47->37,
// Mfma 20->25) but REGRESSED dur 52.6->59.8: the removed v_adds were
// independent ops hidden in existing stalls (free), the added MFMAs
// serialized the matrix pipe's per-round chain (12 vs 8 MFMA). Lesson:
// VALUBusy measures occupied, not critical.
// Session ledger 172.7 -> 141.7us (-18%). Levers closed:
//  - occupancy shapes (R18/19/23/24/25): dur insensitive 52-61us
//  - L2 staging traffic halving via 64-q tiles (R20): +11%
//  - dispatch count (R26/27/28): ~19us/boundary; 3 dispatches is the
//    floor -- in-dispatch cross-block fences cost +195us on the
//    non-coherent per-XCD L2s (R27)
//  - in-loop ILP (R29/30): slot dbuf + vmcnt(5) WAR protocol is only
//    sound at unroll depth 1 (both manual and pragma unroll NaN)
//  - pipe rebalance (R32): regression
// Numerics: M = |Q|*max|K'| - 12, f16 P, f32 lsum.

#define N_PIX 9216
#define N_B   2
#define N_C   64

typedef _Float16 half8  __attribute__((ext_vector_type(8)));
typedef float    float4v __attribute__((ext_vector_type(4)));
typedef float    float16v __attribute__((ext_vector_type(16)));
typedef int      int4v  __attribute__((ext_vector_type(4)));

#define LOG2E 1.44269504088896340736f
#define EXP_SHIFT 12.0f
#define LGKM0() asm volatile("s_waitcnt lgkmcnt(0)" ::: "memory")

// ---------------------------------------------------------------- k_fgh
// 288 blocks x 256 thr: block = (b, 64-pixel span n0).
// Phase A (waves in parallel): sigmas (w0: Wq, w1: Wk, w2: Wv-MFMA) + x->Xh (w3).
// Phase B: Wsh = W/sigma in f16, MFMA f/g/h, staged coalesced stores.
// Writes Kmax[b*144+t144] (deterministic, no atomics).
__global__ __launch_bounds__(256) void k_fgh(const float* __restrict__ x,
                                             const float* __restrict__ Wq, const float* __restrict__ bq,
                                             const float* __restrict__ Wk, const float* __restrict__ bk,
                                             const float* __restrict__ Wv, const float* __restrict__ bv,
                                             _Float16* __restrict__ K16,
                                             _Float16* __restrict__ Q16,
                                             _Float16* __restrict__ VT16,
                                             float* __restrict__ Kmax) {
  __shared__ __align__(16) char SMEM[46624];
  _Float16* Xh  = (_Float16*)SMEM;                    // [64][72] = 9216 B (persist)
  float*    Wl  = (float*)(SMEM + 9216);              // 4096 f32 = 16384 B
  _Float16* Wh  = (_Float16*)(SMEM + 25600);          // [64][80] = 10240 B
  _Float16* Gh  = (_Float16*)(SMEM + 35840);          // [64][80] = 10240 B
  float*    G8q = (float*)(SMEM + 46080);             // 64 f32 (phase A)
  float*    G8k = (float*)(SMEM + 46336);             // 64 f32
  float*    sigs = (float*)(SMEM + 46592);            // 4 f32
  _Float16* Wsh = (_Float16*)(SMEM + 9216);           // [80][64] = 10240 B
  float*    bsh = (float*)(SMEM + 19456);             // 80 f32
  _Float16* Rt  = (_Float16*)(SMEM + 19776);          // [80][72] = 11520 B
  float*    kmx = (float*)(SMEM + 46080);             // 4 f32 (phase B, reuses G8q)

  const int t = threadIdx.x;
  const int wave = t >> 6, lane = t & 63;
  const int tile = blockIdx.x;
  const int b = tile / 144;
  const int t144 = tile % 144;
  const int n0 = t144 * 64;
  const float* xb = x + (size_t)b * N_C * N_PIX;

  // ================= Phase A =================
  if (wave == 3) {
#pragma unroll
    for (int i = 0; i < 16; ++i) {
      const int idx = lane + 64 * i;       // 0..1023
      const int c = idx >> 4, f4 = idx & 15;
      const float4v v = *(const float4v*)(xb + (size_t)c * N_PIX + n0 + 4 * f4);
#pragma unroll
      for (int e = 0; e < 4; ++e) Xh[(4 * f4 + e) * 72 + c] = (_Float16)v[e];
    }
  } else if (wave < 2) {
    const float* W = (wave == 0) ? Wq : Wk;
    float* G8 = (wave == 0) ? G8q : G8k;
    const int i = lane >> 3, j = lane & 7;
    float g = 0.f;
    for (int c = 0; c < 64; ++c) g += W[i * 64 + c] * W[j * 64 + c];
    G8[lane] = g;
    LGKM0();
    const int L = lane & 7;
    float G0[8], Gr[8];
    for (int k = 0; k < 8; ++k) { G0[k] = G8[L * 8 + k]; Gr[k] = G0[k]; }
    for (int it = 0; it < 8; ++it) {
      float g2[8] = {0, 0, 0, 0, 0, 0, 0, 0};
      for (int k = 0; k < 8; ++k) {
        float gik = Gr[k];
        for (int jj = 0; jj < 8; ++jj) g2[jj] += gik * __shfl(Gr[jj], k, 64);
      }
      float mx = 0.f;
      for (int jj = 0; jj < 8; ++jj) mx = fmaxf(mx, fabsf(g2[jj]));
      for (int d = 1; d < 8; d <<= 1) mx = fmaxf(mx, __shfl_xor(mx, d, 64));
      float r = 1.f / mx;
      for (int jj = 0; jj < 8; ++jj) Gr[jj] = g2[jj] * r;
    }
    float u = 0.f;
    for (int jj = 0; jj < 8; ++jj) u += Gr[jj];
    float y = 0.f;
    for (int k = 0; k < 8; ++k) y += G0[k] * __shfl(u, k, 64);
    float nu = u * y, de = u * u;
    for (int d = 1; d < 8; d <<= 1) { nu += __shfl_xor(nu, d, 64); de += __shfl_xor(de, d, 64); }
    if (lane == 0) sigs[wave] = sqrtf(nu / de);
  } else {
#pragma unroll
    for (int i = 0; i < 16; ++i) {
      const int idx = lane + 64 * i;
      *(float4v*)&Wl[4 * idx] = *(const float4v*)&Wv[4 * idx];
    }
    LGKM0();
    for (int idx = lane; idx < 4096; idx += 64)
      Wh[(idx >> 6) * 80 + (idx & 63)] = (_Float16)Wl[idx];
    LGKM0();
    const int lane15 = lane & 15, quad = lane >> 4;
    half8 fr[4][2];
    for (int rb = 0; rb < 4; ++rb)
      for (int kc = 0; kc < 2; ++kc)
        fr[rb][kc] = *(const half8*)&Wh[(lane15 + 16 * rb) * 80 + 32 * kc + 8 * quad];
    float4v D[4][4];
    for (int mb = 0; mb < 4; ++mb) for (int nb = 0; nb < 4; ++nb) D[mb][nb] = (float4v){0.f, 0.f, 0.f, 0.f};
    for (int kc = 0; kc < 2; ++kc)
      for (int mb = 0; mb < 4; ++mb)
        for (int nb = 0; nb < 4; ++nb)
          D[mb][nb] = __builtin_amdgcn_mfma_f32_16x16x32_f16(fr[mb][kc], fr[nb][kc], D[mb][nb], 0, 0, 0);
    for (int it = 0; it < 8; ++it) {
      float mx = 0.f;
      for (int mb = 0; mb < 4; ++mb) for (int nb = 0; nb < 4; ++nb) for (int r = 0; r < 4; ++r)
        mx = fmaxf(mx, fabsf(D[mb][nb][r]));
      for (int d = 1; d < 64; d <<= 1) mx = fmaxf(mx, __shfl_xor(mx, d, 64));
      const float rs = 1.f / mx;
      LGKM0();
      for (int mb = 0; mb < 4; ++mb) for (int nb = 0; nb < 4; ++nb) for (int r = 0; r < 4; ++r)
        Gh[(4 * quad + r + 16 * mb) * 80 + lane15 + 16 * nb] = (_Float16)(D[mb][nb][r] * rs);
      LGKM0();
      if (it == 7) break;
      for (int rb = 0; rb < 4; ++rb)
        for (int kc = 0; kc < 2; ++kc)
          fr[rb][kc] = *(const half8*)&Gh[(lane15 + 16 * rb) * 80 + 32 * kc + 8 * quad];
      for (int mb = 0; mb < 4; ++mb) for (int nb = 0; nb < 4; ++nb) D[mb][nb] = (float4v){0.f, 0.f, 0.f, 0.f};
      for (int kc = 0; kc < 2; ++kc)
        for (int mb = 0; mb < 4; ++mb)
          for (int nb = 0; nb < 4; ++nb)
            D[mb][nb] = __builtin_amdgcn_mfma_f32_16x16x32_f16(fr[mb][kc], fr[nb][kc], D[mb][nb], 0, 0, 0);
    }
    float u = 0.f;
    for (int c = 0; c < 64; ++c) u += (float)Gh[lane * 80 + c];
    float z = 0.f;
    for (int i2 = 0; i2 < 64; ++i2) z += Wl[i2 * 64 + lane] * __shfl(u, i2, 64);
    float nu = z * z, de = u * u;
    for (int d = 1; d < 64; d <<= 1) { nu += __shfl_xor(nu, d, 64); de += __shfl_xor(de, d, 64); }
    if (lane == 0) sigs[2] = sqrtf(nu / de);
  }
  __syncthreads();

  // ================= Phase B =================
  const float iq = LOG2E / sigs[0], ik = 1.0f / sigs[1], iv = 1.0f / sigs[2];
  __syncthreads();                         // sigs read before overlay reuse
  for (int idx = t; idx < 80 * 64; idx += 256) {
    const int m = idx >> 6, c = idx & 63;
    float v;
    if (m < 8)       v = Wq[m * 64 + c] * iq;
    else if (m < 16) v = Wk[(m - 8) * 64 + c] * ik;
    else             v = Wv[(m - 16) * 64 + c] * iv;
    Wsh[idx] = (_Float16)v;
  }
  if (t < 80) {
    float v;
    if (t < 8)       v = bq[t] * LOG2E;
    else if (t < 16) v = bk[t - 8];
    else             v = bv[t - 16];
    bsh[t] = v;
  }
  __syncthreads();
  const int lane15 = lane & 15, quad = lane >> 4;
  const int nl = 16 * wave + lane15;
  half8 wf[5][2];
  for (int mb = 0; mb < 5; ++mb)
    for (int kc = 0; kc < 2; ++kc)
      wf[mb][kc] = *(const half8*)&Wsh[(lane15 + 16 * mb) * 64 + 32 * kc + 8 * quad];
  float4v acc[5];
  for (int mb = 0; mb < 5; ++mb) acc[mb] = *(const float4v*)&bsh[16 * mb + 4 * quad];
  for (int kc = 0; kc < 2; ++kc) {
    const half8 bf = *(const half8*)&Xh[nl * 72 + 32 * kc + 8 * quad];
    for (int mb = 0; mb < 5; ++mb)
      acc[mb] = __builtin_amdgcn_mfma_f32_16x16x32_f16(wf[mb][kc], bf, acc[mb], 0, 0, 0);
  }
#pragma unroll
  for (int r = 0; r < 4; ++r) Rt[(4 * quad + r) * 72 + nl] = (_Float16)acc[0][r];
  for (int mb = 1; mb < 5; ++mb)
#pragma unroll
    for (int r = 0; r < 4; ++r) {
      const int c = 4 * quad + r + 16 * (mb - 1);
      Rt[(16 + c) * 72 + nl] = (_Float16)acc[mb][r];
    }
  // block max of ||K_pix||^2 -> Kmax (deterministic).
  float sq = 0.f;
  if (quad < 2)
    for (int r = 0; r < 4; ++r) sq += acc[0][r] * acc[0][r];
  sq += __shfl_xor(sq, 16, 64);
  for (int d = 1; d < 64; d <<= 1) sq = fmaxf(sq, __shfl_xor(sq, d, 64));
  if (lane == 0) kmx[wave] = sq;
  __syncthreads();
  if (t == 0) Kmax[b * 144 + t144] = fmaxf(fmaxf(kmx[0], kmx[1]), fmaxf(kmx[2], kmx[3]));
  if (t < 64) {                            // K16[n][0..8): dwordx4/thread
    const int n = t;
    int4v dw;
#pragma unroll
    for (int mw = 0; mw < 4; ++mw) {
      const unsigned lo = (unsigned)__builtin_bit_cast(unsigned short, Rt[(2 * mw) * 72 + n]);
      const unsigned hi = (unsigned)__builtin_bit_cast(unsigned short, Rt[(2 * mw + 1) * 72 + n]);
      dw[mw] = (int)(lo | (hi << 16));
    }
    *(int4v*)(K16 + ((size_t)b * N_PIX + n0 + n) * 8) = dw;
  } else if (t < 128) {                    // Q16[n][0..8)
    const int n = t - 64;
    int4v dw;
#pragma unroll
    for (int mw = 0; mw < 4; ++mw) {
      const unsigned lo = (unsigned)__builtin_bit_cast(unsigned short, Rt[(8 + 2 * mw) * 72 + n]);
      const unsigned hi = (unsigned)__builtin_bit_cast(unsigned short, Rt[(9 + 2 * mw) * 72 + n]);
      dw[mw] = (int)(lo | (hi << 16));
    }
    *(int4v*)(Q16 + ((size_t)b * N_PIX + n0 + n) * 8) = dw;
  }
  {                                        // VT16[c][n0..+64): 32B/thread
    const int c = t >> 2, part = t & 3;
    const _Float16* src = &Rt[(16 + c) * 72 + 16 * part];
    const int4v a = *(const int4v*)src;
    const int4v b2 = *(const int4v*)(src + 8);
    _Float16* dst = VT16 + ((size_t)b * N_C + c) * N_PIX + n0 + 16 * part;
    *(int4v*)dst = a;
    *(int4v*)(dst + 8) = b2;
  }
}

// ---------------------------------------------------------------- k_attn
// 864 blocks x 256 threads (4 waves): tile = b*432 + qt*3 + h; block covers
// queries [qt*64, +64) (two 32-q tiles) and keys [3072h, +3072), 24 rounds
// of 128 keys (wave w owns 32). K in regs (dbuf); V dbuf in LDS per wave
// (swizzled). Rolled loop (depth-1 REQUIRED: slot dbuf + vmcnt(5) WAR).
// Plain partial writes -- NO fences/atomics (R27 lesson).

__device__ __forceinline__ void gload16(const _Float16* g, _Float16* l) {
  __builtin_amdgcn_global_load_lds(
      (const __attribute__((address_space(1))) void*)g,
      (__attribute__((address_space(3))) void*)l, 16, 0, 0);
}
#define VMWAIT5() asm volatile("s_waitcnt vmcnt(5)" ::: "memory")

// v_permlane32_swap_b32: a' = [a.lo, b.lo], b' = [a.hi, b.hi]
__device__ __forceinline__ void plswap(int& a, int& b) {
  asm("v_permlane32_swap_b32 %0, %1" : "+v"(a), "+v"(b));
}

__global__ __launch_bounds__(256, 2) void k_attn(const _Float16* __restrict__ K16,
                                                 const _Float16* __restrict__ Q16,
                                                 const _Float16* __restrict__ VT16,
                                                 const float* __restrict__ Kmax,
                                                 float* __restrict__ Opart,
                                                 float* __restrict__ Lpart) {
  __shared__ __align__(16) _Float16 SM[4][4096];   // 32768 B -> 4 blocks/CU
  const int wave = threadIdx.x >> 6;      // 0..3
  const int lane = threadIdx.x & 63;
  const int q31 = lane & 31, hi = lane >> 5;
  const int tile = blockIdx.x;            // 0..863
  const int b = tile / 432;
  const int rm = tile % 432;
  const int qt = rm / 3;                  // 0..143 -> queries [qt*64, +64)
  const int h = rm % 3;                   // key split
  const int jb = qt * 64;
  const int kh = h * (N_PIX / 3);         // 3072-key range base
  const _Float16* Kb = K16 + (size_t)b * N_PIX * 8;
  const _Float16* Vb = VT16 + (size_t)b * N_C * N_PIX;
  _Float16* Rg = SM[wave];
  const int cl = lane >> 2, kk = lane & 3;
  const int gsw = (kk ^ ((cl >> 1) & 3)) * 8;
  const int vx = (q31 >> 1) & 3;
  const int voff00 = q31 * 32 + ((hi ^ vx) << 3);
  const int voff01 = q31 * 32 + (((2 + hi) ^ vx) << 3);
  const int voff10 = 1024 + voff00;
  const int voff11 = 1024 + voff01;

  half8 qfA = {}, qfB = {};
  if (hi == 0) {
    qfA = *(const half8*)(Q16 + ((size_t)b * N_PIX + jb + q31) * 8);
    qfB = *(const half8*)(Q16 + ((size_t)b * N_PIX + jb + 32 + q31) * 8);
  }
  // deterministic max||K||^2 over the batch: reduce 144 per-tile maxima.
  float km;
  {
    const float* Km = Kmax + b * 144;
    const float a0 = Km[lane];
    const float a1 = Km[64 + lane];
    const float a2 = (lane < 16) ? Km[128 + lane] : 0.f;
    km = fmaxf(fmaxf(a0, a1), a2);
    for (int d = 1; d < 64; d <<= 1) km = fmaxf(km, __shfl_xor(km, d, 64));
  }
  const float maxK = sqrtf(km);
  float nqA = 0.f, nqB = 0.f;
#pragma unroll
  for (int j = 0; j < 8; ++j) {
    nqA += (float)qfA[j] * (float)qfA[j];
    nqB += (float)qfB[j] * (float)qfB[j];
  }
  nqA += __shfl_xor(nqA, 32, 64);
  nqB += __shfl_xor(nqB, 32, 64);
  const float MA = sqrtf(nqA) * maxK - EXP_SHIFT;
  const float MB = sqrtf(nqB) * maxK - EXP_SHIFT;
  float16v sinitA, sinitB;
#pragma unroll
  for (int r2 = 0; r2 < 16; ++r2) { sinitA[r2] = -MA; sinitB[r2] = -MB; }

  float16v accLo0 = {}, accHi0 = {}, accLo1 = {}, accHi1 = {};
  float lsA = 0.f, lsB = 0.f;

  // softmax: S (f32x16, C-layout, already -M biased) -> P0/P1 (B-layout f16) + l-sum.
  auto softmax = [&](const float16v& s, float& ls, half8& P0, half8& P1) {
    int pk[8];
#pragma unroll
    for (int u = 0; u < 8; ++u) {
      const float p0 = __builtin_amdgcn_exp2f(s[2 * u]);
      const float p1 = __builtin_amdgcn_exp2f(s[2 * u + 1]);
      ls += p0 + p1;
      pk[u] = __builtin_bit_cast(int, __builtin_amdgcn_cvt_pkrtz(p0, p1));
    }
    int p0w = pk[0], p2w = pk[2];  plswap(p0w, p2w);
    int p1w = pk[1], p3w = pk[3];  plswap(p1w, p3w);
    int p4w = pk[4], p6w = pk[6];  plswap(p4w, p6w);
    int p5w = pk[5], p7w = pk[7];  plswap(p5w, p7w);
    int4v B0i, B1i;
    B0i[0] = p0w; B0i[1] = p1w; B0i[2] = p2w; B0i[3] = p3w;
    B1i[0] = p4w; B1i[1] = p5w; B1i[2] = p6w; B1i[3] = p7w;
    P0 = __builtin_bit_cast(half8, B0i);
    P1 = __builtin_bit_cast(half8, B1i);
  };

#define STAGEV(SLOT, I0)                                                         \
  {                                                                              \
    const int _i = (I0);                                                         \
    gload16(Vb + (size_t)cl * N_PIX + _i + gsw,        Rg + (SLOT) * 2048);      \
    gload16(Vb + (size_t)(16 + cl) * N_PIX + _i + gsw, Rg + (SLOT) * 2048 + 512);\
    gload16(Vb + (size_t)(32 + cl) * N_PIX + _i + gsw, Rg + (SLOT) * 2048 + 1024);\
    gload16(Vb + (size_t)(48 + cl) * N_PIX + _i + gsw, Rg + (SLOT) * 2048 + 1536);\
  }

  // K base for this wave's key stream; +1024 halves (128 keys) per round.
  const _Float16* kpt = Kb + (size_t)(kh + 32 * wave + q31) * 8;
  int4v kcur = *(const int4v*)kpt;
  STAGEV(0, kh + 32 * wave)

#pragma unroll 1
  for (int r = 0; r < 24; ++r) {
    const int slot = r & 1, nslot = slot ^ 1;
    // prefetch round r+1 (r=23: clamp -> re-load round 23, never consumed)
    const int rn = (r < 23) ? (r + 1) : 23;
    int4v knext = *(const int4v*)(kpt + (size_t)rn * 1024);
    STAGEV(nslot, kh + 128 * rn + 32 * wave)
    VMWAIT5();
    int4v kcz;
    kcz[0] = hi ? 0 : kcur[0];
    kcz[1] = hi ? 0 : kcur[1];
    kcz[2] = hi ? 0 : kcur[2];
    kcz[3] = hi ? 0 : kcur[3];
    const half8 kf = __builtin_bit_cast(half8, kcz);
    float16v sA = __builtin_amdgcn_mfma_f32_32x32x16_f16(kf, qfA, sinitA, 0, 0, 0);
    half8 P0a, P1a;
    softmax(sA, lsA, P0a, P1a);
    float16v sB = __builtin_amdgcn_mfma_f32_32x32x16_f16(kf, qfB, sinitB, 0, 0, 0);
    half8 P0b, P1b;
    softmax(sB, lsB, P0b, P1b);
    const _Float16* Vs = Rg + slot * 2048;
    const half8 v00 = *(const half8*)&Vs[voff00];
    const half8 v01 = *(const half8*)&Vs[voff01];
    const half8 v10 = *(const half8*)&Vs[voff10];
    const half8 v11 = *(const half8*)&Vs[voff11];
    accLo0 = __builtin_amdgcn_mfma_f32_32x32x16_f16(v00, P0a, accLo0, 0, 0, 0);
    accLo0 = __builtin_amdgcn_mfma_f32_32x32x16_f16(v01, P1a, accLo0, 0, 0, 0);
    accHi0 = __builtin_amdgcn_mfma_f32_32x32x16_f16(v10, P0a, accHi0, 0, 0, 0);
    accHi0 = __builtin_amdgcn_mfma_f32_32x32x16_f16(v11, P1a, accHi0, 0, 0, 0);
    accLo1 = __builtin_amdgcn_mfma_f32_32x32x16_f16(v00, P0b, accLo1, 0, 0, 0);
    accLo1 = __builtin_amdgcn_mfma_f32_32x32x16_f16(v01, P1b, accLo1, 0, 0, 0);
    accHi1 = __builtin_amdgcn_mfma_f32_32x32x16_f16(v10, P0b, accHi1, 0, 0, 0);
    accHi1 = __builtin_amdgcn_mfma_f32_32x32x16_f16(v11, P1b, accHi1, 0, 0, 0);
    kcur = knext;
  }
#undef STAGEV
  asm volatile("s_waitcnt vmcnt(0)" ::: "memory");

  // ---- cross-wave merge (4 passes over 4 waves), partials undivided.
  float* Ow  = (float*)Rg;               // 64 x 17 f32 (stride 17: bank-free)
  float* LwA = (float*)Rg + 1100;        // 32 f32
  float* LwB = (float*)Rg + 1140;        // 32 f32
  lsA += __shfl_xor(lsA, 32, 64);
  lsB += __shfl_xor(lsB, 32, 64);
  if (hi == 0) { LwA[q31] = lsA; LwB[q31] = lsB; }
  float* Op0 = Opart + (size_t)(tile * 2) * 2048;     // sub-tile A
  float* Op1 = Op0 + 2048;                            // sub-tile B
#pragma unroll
  for (int r2 = 0; r2 < 16; ++r2) Ow[lane * 17 + r2] = accLo0[r2];
  __syncthreads();
  float ltotA = 0.f, ltotB = 0.f;
#pragma unroll
  for (int w = 0; w < 4; ++w) {
    ltotA += ((const float*)SM[w])[1100 + q31];
    ltotB += ((const float*)SM[w])[1140 + q31];
  }
  if (wave == 0 && hi == 0) {
    Lpart[(tile * 2) * 32 + q31] = ltotA;
    Lpart[(tile * 2 + 1) * 32 + q31] = ltotB;
  }
#pragma unroll
  for (int r2 = 0; r2 < 16; ++r2) {
    float osum = 0.f;
#pragma unroll
    for (int w = 0; w < 4; ++w) osum += ((const float*)SM[w])[lane * 17 + r2];
    const int c = (r2 & 3) + 8 * (r2 >> 2) + 4 * hi;
    Op0[c * 32 + q31] = osum;
  }
  __syncthreads();
#pragma unroll
  for (int r2 = 0; r2 < 16; ++r2) Ow[lane * 17 + r2] = accHi0[r2];
  __syncthreads();
#pragma unroll
  for (int r2 = 0; r2 < 16; ++r2) {
    float osum = 0.f;
#pragma unroll
    for (int w = 0; w < 4; ++w) osum += ((const float*)SM[w])[lane * 17 + r2];
    const int c = 32 + (r2 & 3) + 8 * (r2 >> 2) + 4 * hi;
    Op0[c * 32 + q31] = osum;
  }
  __syncthreads();
#pragma unroll
  for (int r2 = 0; r2 < 16; ++r2) Ow[lane * 17 + r2] = accLo1[r2];
  __syncthreads();
#pragma unroll
  for (int r2 = 0; r2 < 16; ++r2) {
    float osum = 0.f;
#pragma unroll
    for (int w = 0; w < 4; ++w) osum += ((const float*)SM[w])[lane * 17 + r2];
    const int c = (r2 & 3) + 8 * (r2 >> 2) + 4 * hi;
    Op1[c * 32 + q31] = osum;
  }
  __syncthreads();
#pragma unroll
  for (int r2 = 0; r2 < 16; ++r2) Ow[lane * 17 + r2] = accHi1[r2];
  __syncthreads();
#pragma unroll
  for (int r2 = 0; r2 < 16; ++r2) {
    float osum = 0.f;
#pragma unroll
    for (int w = 0; w < 4; ++w) osum += ((const float*)SM[w])[lane * 17 + r2];
    const int c = 32 + (r2 & 3) + 8 * (r2 >> 2) + 4 * hi;
    Op1[c * 32 + q31] = osum;
  }
}

// ---------------------------------------------------------------- k_merge
// 576 blocks (b, jt32): out = gm*(sum of 3 key-split partials)/(l sum) + x.
__global__ __launch_bounds__(256) void k_merge(const float* __restrict__ Opart,
                                               const float* __restrict__ Lpart,
                                               const float* __restrict__ x,
                                               const float* __restrict__ gamma,
                                               float* __restrict__ out) {
  __shared__ float Ls[32];
  const int t2 = blockIdx.x;              // 0..575
  const int b = t2 / 288, jt = t2 % 288;  // jt: 32-query tile index
  const int jb = jt * 32;
  const int qt = jt >> 1, sub = jt & 1;
  const int g0 = b * 432 + qt * 3;        // 3 key-split partials
  const float gm = gamma[0];
  const int t = threadIdx.x;
  if (t < 32)
    Ls[t] = Lpart[((g0 + 0) * 2 + sub) * 32 + t] +
            Lpart[((g0 + 1) * 2 + sub) * 32 + t] +
            Lpart[((g0 + 2) * 2 + sub) * 32 + t];
  __syncthreads();
  const float* O0 = Opart + (size_t)((g0 + 0) * 2 + sub) * 2048;
  const float* O1 = Opart + (size_t)((g0 + 1) * 2 + sub) * 2048;
  const float* O2 = Opart + (size_t)((g0 + 2) * 2 + sub) * 2048;
  const float* xb = x + (size_t)b * N_C * N_PIX;
  float* ob = out + (size_t)b * N_C * N_PIX;
#pragma unroll
  for (int k = 0; k < 8; ++k) {
    const int idx = t + 256 * k;
    const int c = idx >> 5, q = idx & 31;
    const size_t gi = (size_t)c * N_PIX + jb + q;
    ob[gi] = gm * (O0[idx] + O1[idx] + O2[idx]) / Ls[q] + xb[gi];
  }
}

// ---------------------------------------------------------------- launch
extern "C" void kernel_launch(void* const* d_in, const int* in_sizes, int n_in,
                              void* d_out, int out_size, void* d_ws, size_t ws_size,
                              hipStream_t stream) {
  const float* x     = (const float*)d_in[0];
  const float* Wq    = (const float*)d_in[1];
  const float* bq    = (const float*)d_in[2];
  const float* Wk    = (const float*)d_in[3];
  const float* bk    = (const float*)d_in[4];
  const float* Wv    = (const float*)d_in[5];
  const float* bv    = (const float*)d_in[6];
  const float* gamma = (const float*)d_in[7];
  float* out = (float*)d_out;

  char* ws = (char*)d_ws;
  float*    Kmax  = (float*)ws;                       // 288 f32 = 1152 B
  _Float16* K16   = (_Float16*)(ws + 10752);          // 294912 B
  _Float16* Q16   = (_Float16*)(ws + 10752 + 294912); // 294912 B
  _Float16* VT16  = (_Float16*)(ws + 10752 + 2 * 294912); // 2359296 B
  float*    Opart = (float*)(ws + 2960384);           // 864*2*2048*4 = 14155776 B
  float*    Lpart = (float*)(ws + 2960384 + 14155776); // 864*2*32*4 = 221184 B

  hipLaunchKernelGGL(k_fgh, dim3(288), dim3(256), 0, stream,
                     x, Wq, bq, Wk, bk, Wv, bv, K16, Q16, VT16, Kmax);
  hipLaunchKernelGGL(k_attn, dim3(864), dim3(256), 0, stream,
                     K16, Q16, VT16, Kmax, Opart, Lpart);
  hipLaunchKernelGGL(k_merge, dim3(576), dim3(256), 0, stream, Opart, Lpart, x, gamma, out);
}